// Round 10
// baseline (58.971 us; speedup 1.0000x reference)
//
#include <hip/hip_runtime.h>

// Problem constants (match reference)
#define PP 32
#define SS 4
#define CC 64
#define HH 128
#define WW 128
#define NC 32
#define OO 32
#define PLANE (HH * WW)

// ws: int cbase[PP*NC]; int psize[PP]
// cbase[p*NC+c] = element offset of crop origin (offy*W + offx included)
// in the (p, s=0, channels[p][c]) plane.
__global__ __launch_bounds__(256) void setup_kernel(
    const int* __restrict__ size_raw,
    const int* __restrict__ pix,
    const int* __restrict__ channels,
    int*       __restrict__ cbase,   // [PP*NC]
    int*       __restrict__ psize)   // [PP]
{
    const int i = blockIdx.x * 256 + threadIdx.x;   // 0..1023
    const int p = i >> 5;
    const int c = i & 31;
    const int size = size_raw[p] + OO;              // [32,128]
    const int wr = WW - size + 1;
    const int hr = HH - size + 1;
    const int pm = pix[p] % (wr * hr);
    const int offy = pm / wr;
    const int offx = pm - offy * wr;
    if (c == 0) psize[p] = size;
    const int ch = channels[p * NC + c];
    cbase[i] = (p * SS * CC + ch) * PLANE + offy * WW + offx;
}

// One 256-thread block per (p,s,c) crop. Separable pooling with MLP:
// Phase 1: lane x (=t&127) owns crop column x; each half (h=t>>7) covers 16
//   o-bins, processed 4 AT A TIME (static 5x4 load grid, exec-masked) ->
//   up to 16 independent loads in flight per lane, no serial chains.
//   Column sums -> LDS cs[32][129]. Each crop element loaded ~1.25x (bin
//   row-overlap only); L2 traffic ~220 MB vs 670 MB in the per-output kernel.
// Phase 2: one barrier; each thread -> 4 consecutive q outputs, static-5
//   masked LDS reads per bin, one contiguous float4 store.
__global__ __launch_bounds__(256) void pool_kernel(
    const float* __restrict__ input,   // [P,S,C,H,W]
    const int*   __restrict__ cbase,   // [PP*NC]
    const int*   __restrict__ psize,   // [PP]
    float*       __restrict__ out)     // [P,S,NC,O,O]
{
    __shared__ float cs[OO][129];

    const int blk = blockIdx.x;        // (p<<7)|(s<<5)|c
    const int c = blk & (NC - 1);
    const int s = (blk >> 5) & (SS - 1);
    const int p = blk >> 7;
    const int t = threadIdx.x;
    const int x = t & 127;             // crop column owned by this lane
    const int h = t >> 7;              // o-half (0: o<16, 1: o>=16)

    const int size = psize[p];         // wave-uniform
    const float* base = input + cbase[(p << 5) | c] + s * (CC * PLANE) + x;
    const bool xv = (x < size);

    #pragma unroll
    for (int og = 0; og < 4; ++og) {
        int   rws[4];
        const float* ptr[4];
        float acc[4];
        #pragma unroll
        for (int k = 0; k < 4; ++k) {
            const int o  = (h << 4) + (og << 2) + k;
            const int sy = (o * size) >> 5;
            rws[k] = (((o + 1) * size + 31) >> 5) - sy;   // 1..5
            ptr[k] = base + sy * WW;
            acc[k] = 0.0f;
        }
        // 5x4 static grid of independent, exec-masked loads
        #pragma unroll
        for (int r = 0; r < 5; ++r) {
            #pragma unroll
            for (int k = 0; k < 4; ++k) {
                if (xv && r < rws[k]) acc[k] += ptr[k][r * WW];
            }
        }
        #pragma unroll
        for (int k = 0; k < 4; ++k)
            cs[(h << 4) + (og << 2) + k][x] = acc[k];
    }
    __syncthreads();

    // Phase 2: outputs i0..i0+3 of this block's 32x32 tile
    const int i0 = t << 2;
    const int q0 = i0 & (OO - 1);
    const int o  = i0 >> 5;
    const int rows = (((o + 1) * size + 31) >> 5) - ((o * size) >> 5);
    const float fr = (float)rows;

    float res[4];
    #pragma unroll
    for (int j = 0; j < 4; ++j) {
        const int q  = q0 + j;
        const int sx = (q * size) >> 5;
        const int cols = ((((q + 1) * size + 31) >> 5)) - sx;   // 1..5
        float a = 0.0f;
        #pragma unroll
        for (int u = 0; u < 5; ++u) {
            const float v = cs[o][sx + u];         // sx+4 <= 128 < 129: in-bounds
            a += (u < cols) ? v : 0.0f;            // select (never multiply garbage)
        }
        res[j] = a * __builtin_amdgcn_rcpf(fr * (float)cols);
    }
    *(float4*)(out + ((size_t)blk << 10) + i0) =
        make_float4(res[0], res[1], res[2], res[3]);
}

extern "C" void kernel_launch(void* const* d_in, const int* in_sizes, int n_in,
                              void* d_out, int out_size, void* d_ws, size_t ws_size,
                              hipStream_t stream) {
    const float* input    = (const float*)d_in[0];
    const int*   size_raw = (const int*)d_in[1];
    const int*   pix      = (const int*)d_in[2];
    const int*   channels = (const int*)d_in[3];
    float*       out      = (float*)d_out;

    int* cbase = (int*)d_ws;            // 1024 ints
    int* psize = cbase + PP * NC;       // 32 ints

    setup_kernel<<<4, 256, 0, stream>>>(size_raw, pix, channels, cbase, psize);

    const int grid = PP * SS * NC;      // 4096 blocks
    pool_kernel<<<grid, 256, 0, stream>>>(input, cbase, psize, out);
}

// Round 11
// 34.445 us; speedup vs baseline: 1.7120x; 1.7120x over previous
//
#include <hip/hip_runtime.h>

// Problem constants (match reference)
#define PP 32
#define SS 4
#define CC 64
#define HH 128
#define WW 128
#define NC 32
#define OO 32
#define PLANE (HH * WW)
#define NTOT (PP * SS * CC * PLANE)   // 33,554,432 elements

// ws: int cbase[PP*NC]; int psize[PP]
__global__ __launch_bounds__(256) void setup_kernel(
    const int* __restrict__ size_raw,
    const int* __restrict__ pix,
    const int* __restrict__ channels,
    int*       __restrict__ cbase,   // [PP*NC]
    int*       __restrict__ psize)   // [PP]
{
    const int i = blockIdx.x * 256 + threadIdx.x;   // 0..1023
    const int p = i >> 5;
    const int c = i & 31;
    const int size = size_raw[p] + OO;              // [32,128]
    const int wr = WW - size + 1;
    const int hr = HH - size + 1;
    const int pm = pix[p] % (wr * hr);
    const int offy = pm / wr;
    const int offx = pm - offy * wr;
    if (c == 0) psize[p] = size;
    const int ch = channels[p * NC + c];
    cbase[i] = (p * SS * CC + ch) * PLANE + offy * WW + offx;
}

// One thread per output element (R8 structure), with predicated loads:
//  - row loads only for dy < rows (wave spans 2 o-values -> near-uniform mask)
//  - second float4 only when the bin window extends past 4 floats
// All loads are zero-init + issued in one grouped pass (no FMAs between) ->
// MLP preserved; reduction afterwards with precomputed scaled masks.
__global__ __launch_bounds__(256) void pool_kernel(
    const float* __restrict__ input,   // [P,S,C,H,W]
    const int*   __restrict__ cbase,   // [PP*NC]
    const int*   __restrict__ psize,   // [PP]
    float*       __restrict__ out)     // [P,S,NC,O,O]
{
    const int idx = blockIdx.x * 256 + threadIdx.x;
    const int q = idx & (OO - 1);
    const int o = (idx >> 5) & (OO - 1);
    const int c = (idx >> 10) & (NC - 1);
    const int s = (idx >> 15) & (SS - 1);
    const int p = idx >> 17;

    const int size = psize[p];                            // wave-uniform
    const int sy = (o * size) >> 5;
    const int rows = (((o + 1) * size + 31) >> 5) - sy;   // 1..5
    const int sx = (q * size) >> 5;
    const int cols = (((q + 1) * size + 31) >> 5) - sx;   // 1..5

    // absolute element offset of bin start; align to 16B
    const int abs0 = cbase[(p << 5) | c] + s * (CC * PLANE) + sy * WW + sx;
    const int sh = abs0 & 3;
    const int a0 = abs0 - sh;
    const bool need2 = (sh + cols) > 4;

    const float rscale = __builtin_amdgcn_rcpf((float)(rows * cols));

    // window masks with scale folded in: position j active iff (j-sh) in [0,cols)
    float m[8];
    #pragma unroll
    for (int j = 0; j < 8; ++j)
        m[j] = ((unsigned)(j - sh) < (unsigned)cols) ? rscale : 0.0f;

    float4 A[5], B[5];
    #pragma unroll
    for (int dy = 0; dy < 5; ++dy) {
        A[dy] = make_float4(0.f, 0.f, 0.f, 0.f);
        B[dy] = make_float4(0.f, 0.f, 0.f, 0.f);
    }
    // grouped predicated loads (no dependent VALU in between -> deep MLP)
    #pragma unroll
    for (int dy = 0; dy < 5; ++dy) {
        if (dy < rows) {
            int ro = a0 + dy * WW;
            ro = (ro > NTOT - 8) ? (NTOT - 8) : ro;       // keep in-bounds+aligned
            A[dy] = *(const float4*)(input + ro);
            if (need2) B[dy] = *(const float4*)(input + ro + 4);
        }
    }

    float acc = 0.0f;
    #pragma unroll
    for (int dy = 0; dy < 5; ++dy) {
        acc += m[0] * A[dy].x + m[1] * A[dy].y + m[2] * A[dy].z + m[3] * A[dy].w
             + m[4] * B[dy].x + m[5] * B[dy].y + m[6] * B[dy].z + m[7] * B[dy].w;
    }
    out[idx] = acc;
}

extern "C" void kernel_launch(void* const* d_in, const int* in_sizes, int n_in,
                              void* d_out, int out_size, void* d_ws, size_t ws_size,
                              hipStream_t stream) {
    const float* input    = (const float*)d_in[0];
    const int*   size_raw = (const int*)d_in[1];
    const int*   pix      = (const int*)d_in[2];
    const int*   channels = (const int*)d_in[3];
    float*       out      = (float*)d_out;

    int* cbase = (int*)d_ws;            // 1024 ints
    int* psize = cbase + PP * NC;       // 32 ints

    setup_kernel<<<4, 256, 0, stream>>>(size_raw, pix, channels, cbase, psize);

    const int total = PP * SS * NC * OO * OO;   // 4,194,304
    pool_kernel<<<total / 256, 256, 0, stream>>>(input, cbase, psize, out);
}